// Round 5
// baseline (1856.936 us; speedup 1.0000x reference)
//
#include <hip/hip_runtime.h>
#include <hip/hip_bf16.h>
#include <hip/hip_fp16.h>

#define B_ 256
#define T_ 4096
#define I_ 64
#define H_ 36
#define G_ 144   // 4*H
#define O_ 2
#define TS 32    // timesteps per LDS tile

typedef __fp16 h2 __attribute__((ext_vector_type(2)));

__device__ __forceinline__ float fsigmoid(float x) {
  float e = __builtin_amdgcn_exp2f(x * -1.442695040888963f);
  return __builtin_amdgcn_rcpf(1.0f + e);
}
__device__ __forceinline__ float ftanh(float x) {
  float e = __builtin_amdgcn_exp2f(x * 2.885390081777926f);
  return 1.0f - 2.0f * __builtin_amdgcn_rcpf(1.0f + e);
}
__device__ __forceinline__ h2 pack2(float lo, float hi) {
  return __builtin_amdgcn_cvt_pkrtz(lo, hi);
}
__device__ __forceinline__ float fdot2(h2 a, h2 b, float c) {
  return __builtin_amdgcn_fdot2(a, b, c, false);
}

// ---------------- xg = x @ W_ih^T + (b_ih+b_hh), fp16-packed ----------------
// out[(tile*B + b)*TS + s][j] = uint2{ pack(i,f), pack(g,o) }
// thread col mapping: tc in [0,12), c = tc + 12*q  -> one thread owns all 4
// gates of j = tc + 12*jq (jq=0..2), enabling the 8B pack locally.
__global__ __launch_bounds__(256) void xg_gemm(
    const float* __restrict__ x,      // [nT][B][64] (chunk-local)
    const float* __restrict__ W_ih,   // [144][64]
    const float* __restrict__ b_ih,
    const float* __restrict__ b_hh,
    uint2* __restrict__ xg)           // [nT/TS][B][TS][36] uint2
{
  __shared__ float Wt[64 * 145];
  __shared__ float xt[64 * 68];
  __shared__ float bias[G_];

  const int tid = threadIdx.x;
  for (int idx = tid; idx < G_ * I_; idx += 256) {
    int g = idx >> 6, k = idx & 63;
    Wt[k * 145 + g] = W_ih[idx];
  }
  if (tid < G_) bias[tid] = b_ih[tid] + b_hh[tid];

  const long r0 = (long)blockIdx.x * 64;
  const float4* xin = (const float4*)(x + r0 * I_);
#pragma unroll
  for (int v = 0; v < 4; v++) {
    int idx = tid + v * 256;
    float4 d = xin[idx];
    int r = idx >> 4;
    int kk = (idx & 15) << 2;
    xt[(kk + 0) * 68 + r] = d.x;
    xt[(kk + 1) * 68 + r] = d.y;
    xt[(kk + 2) * 68 + r] = d.z;
    xt[(kk + 3) * 68 + r] = d.w;
  }
  __syncthreads();

  const int tr = tid >> 4;            // 0..15 -> 4 rows each
  const int tc = tid & 15;            // only tc<12 compute (12 x 12 cols)

  if (tc < 12) {
    float acc[4][12];
#pragma unroll
    for (int rr = 0; rr < 4; rr++)
#pragma unroll
      for (int q = 0; q < 12; q++) acc[rr][q] = 0.0f;

#pragma unroll 4
    for (int k = 0; k < 64; k++) {
      float4 xv = *(const float4*)&xt[k * 68 + (tr << 2)];
      const float* wr = &Wt[k * 145 + tc];
#pragma unroll
      for (int q = 0; q < 12; q++) {
        float w = wr[12 * q];
        acc[0][q] = fmaf(xv.x, w, acc[0][q]);
        acc[1][q] = fmaf(xv.y, w, acc[1][q]);
        acc[2][q] = fmaf(xv.z, w, acc[2][q]);
        acc[3][q] = fmaf(xv.w, w, acc[3][q]);
      }
    }

#pragma unroll
    for (int rr = 0; rr < 4; rr++) {
      long r = r0 + (tr << 2) + rr;          // r = t_local*B + b
      int t = (int)(r >> 8);                 // B_ = 256
      int b = (int)(r & 255);
      uint2* out = xg + (((size_t)(t >> 5) * B_ + b) * TS + (t & 31)) * 36;
#pragma unroll
      for (int jq = 0; jq < 3; jq++) {
        int j = tc + 12 * jq;
        float ai = acc[rr][jq]     + bias[j];
        float af = acc[rr][jq + 3] + bias[j + 36];
        float ag = acc[rr][jq + 6] + bias[j + 72];
        float ao = acc[rr][jq + 9] + bias[j + 108];
        uint2 u;
        u.x = __builtin_bit_cast(unsigned int, pack2(ai, af));
        u.y = __builtin_bit_cast(unsigned int, pack2(ag, ao));
        out[j] = u;
      }
    }
  }
}

// broadcast helper: build (h[2t], h[2t+1]) half2 on even lanes, no DS ops.
__device__ __forceinline__ int pack_pair_dpp(float hj) {
  // quad_perm [1,1,3,3]: even lanes receive neighbor lane j+1
  int hn_i = __builtin_amdgcn_update_dpp(0, __float_as_int(hj), 0xF5, 0xF, 0xF, true);
  float hn = __int_as_float(hn_i);
  return __builtin_bit_cast(int, pack2(hj, hn));
}

// ---------------- LSTM scan: wave0 = compute, wave1 = LDS prefetch ----------------
__global__ __launch_bounds__(128, 1) void lstm_scan(
    const uint2* __restrict__ xgT,    // [nT/TS][B][TS][36] uint2 (chunk-local)
    const float* __restrict__ W_hh,   // [144][36]
    const float* __restrict__ W_out,  // [2][36]
    const float* __restrict__ b_out,  // [2]
    float* __restrict__ y,            // [T][B][2] fp32
    float* __restrict__ hc,           // [2][B][36]
    int t0, int nT)
{
  __shared__ float4 buf4[2][576];     // 2 x 32steps x 36 x 8B = 18.4 KiB
  const int b = blockIdx.x;
  const int tid = threadIdx.x;
  const int j = tid & 63;
  const int ntiles = nT / TS;

  h2 wpi[18], wpf[18], wpg[18], wpo[18];
  float hj = 0.0f, cj = 0.0f, yb = 0.0f;
  int jj = 0;

  if (tid < 64) {
    if (j < H_) {
#pragma unroll
      for (int t = 0; t < 18; t++) {
        wpi[t] = pack2(W_hh[j * H_ + 2 * t],             W_hh[j * H_ + 2 * t + 1]);
        wpf[t] = pack2(W_hh[(j + H_) * H_ + 2 * t],      W_hh[(j + H_) * H_ + 2 * t + 1]);
        wpg[t] = pack2(W_hh[(j + 2 * H_) * H_ + 2 * t],  W_hh[(j + 2 * H_) * H_ + 2 * t + 1]);
        wpo[t] = pack2(W_hh[(j + 3 * H_) * H_ + 2 * t],  W_hh[(j + 3 * H_) * H_ + 2 * t + 1]);
      }
    } else if (j < H_ + O_) {
      const int o = j - H_;
#pragma unroll
      for (int t = 0; t < 18; t++) {
        wpi[t] = pack2(W_out[o * H_ + 2 * t], W_out[o * H_ + 2 * t + 1]);
        wpf[t] = pack2(0.f, 0.f); wpg[t] = pack2(0.f, 0.f); wpo[t] = pack2(0.f, 0.f);
      }
      yb = b_out[o];
    } else {
#pragma unroll
      for (int t = 0; t < 18; t++) {
        wpi[t] = pack2(0.f, 0.f); wpf[t] = pack2(0.f, 0.f);
        wpg[t] = pack2(0.f, 0.f); wpo[t] = pack2(0.f, 0.f);
      }
    }
    if (t0 > 0 && j < H_) {
      hj = hc[b * H_ + j];
      cj = hc[B_ * H_ + b * H_ + j];
    }
    jj = (j < H_) ? j : 0;
  }

  // ---- prologue: stage tile 0 (wave 1) ----
  if (tid >= 64) {
    const int pl = tid - 64;
    const float4* src = (const float4*)(xgT + (size_t)b * (TS * 36));
#pragma unroll
    for (int q = 0; q < 9; q++) buf4[0][q * 64 + pl] = src[q * 64 + pl];
  }
  __syncthreads();

  for (int tile = 0; tile < ntiles; ++tile) {
    if (tid >= 64) {
      if (tile + 1 < ntiles) {
        const int pl = tid - 64;
        const float4* src = (const float4*)(xgT + ((size_t)(tile + 1) * B_ + b) * (TS * 36));
        float4* dst = &buf4[(tile + 1) & 1][0];
        float4 tmp[9];
#pragma unroll
        for (int q = 0; q < 9; q++) tmp[q] = src[q * 64 + pl];
#pragma unroll
        for (int q = 0; q < 9; q++) dst[q * 64 + pl] = tmp[q];
      }
    } else {
      const uint2* bp = (const uint2*)&buf4[tile & 1][0];
      uint2 pc = bp[jj];
      for (int s = 0; s < TS; ++s) {
        uint2 pn = bp[((s + 1) & (TS - 1)) * 36 + jj];  // prefetch next step

        // init accumulators (2 per gate -> 9-deep chains)
        h2 v0 = __builtin_bit_cast(h2, pc.x);   // (i,f)
        h2 v1 = __builtin_bit_cast(h2, pc.y);   // (g,o)
        float a_i0, a_f0, a_g0, a_o0;
        if (j < H_) {
          a_i0 = (float)v0.x; a_f0 = (float)v0.y;
          a_g0 = (float)v1.x; a_o0 = (float)v1.y;
        } else {
          a_i0 = yb; a_f0 = 0.f; a_g0 = 0.f; a_o0 = 0.f;
        }
        float a_i1 = 0.f, a_f1 = 0.f, a_g1 = 0.f, a_o1 = 0.f;

        // broadcast h pairs: DPP pack + 18 readlanes (no DS ops on chain)
        int hpi = pack_pair_dpp(hj);
        int hb[18];
#pragma unroll
        for (int t = 0; t < 18; ++t) hb[t] = __builtin_amdgcn_readlane(hpi, 2 * t);
#pragma unroll
        for (int t = 0; t < 18; t += 2) {
          h2 hh0 = __builtin_bit_cast(h2, hb[t]);
          h2 hh1 = __builtin_bit_cast(h2, hb[t + 1]);
          a_i0 = fdot2(wpi[t], hh0, a_i0);  a_i1 = fdot2(wpi[t + 1], hh1, a_i1);
          a_f0 = fdot2(wpf[t], hh0, a_f0);  a_f1 = fdot2(wpf[t + 1], hh1, a_f1);
          a_g0 = fdot2(wpg[t], hh0, a_g0);  a_g1 = fdot2(wpg[t + 1], hh1, a_g1);
          a_o0 = fdot2(wpo[t], hh0, a_o0);  a_o1 = fdot2(wpo[t + 1], hh1, a_o1);
        }
        float a_i = a_i0 + a_i1;

        if (j < H_) {
          float ig = fsigmoid(a_i);
          float fg = fsigmoid(a_f0 + a_f1);
          float gg = ftanh(a_g0 + a_g1);
          float og = fsigmoid(a_o0 + a_o1);
          cj = fg * cj + ig * gg;
          hj = og * ftanh(cj);
        } else if (j < H_ + O_) {
          int gt = t0 + tile * TS + s - 1;
          if (gt >= 0) y[((size_t)gt * B_ + b) * O_ + (j - H_)] = a_i;
        }
        pc = pn;
      }
    }
    __syncthreads();
  }

  // ---- epilogue: last y of chunk + state carry ----
  if (tid < 64) {
    int hpi = pack_pair_dpp(hj);
    float a = yb;
#pragma unroll
    for (int t = 0; t < 18; ++t) {
      int hb = __builtin_amdgcn_readlane(hpi, 2 * t);
      h2 hh = __builtin_bit_cast(h2, hb);
      a = fdot2(wpi[t], hh, a);
    }
    if (j == H_ || j == H_ + 1) {
      y[((size_t)(t0 + nT - 1) * B_ + b) * O_ + (j - H_)] = a;
    }
    if (j < H_) {
      hc[b * H_ + j] = hj;
      hc[B_ * H_ + b * H_ + j] = cj;
    }
  }
}

extern "C" void kernel_launch(void* const* d_in, const int* in_sizes, int n_in,
                              void* d_out, int out_size, void* d_ws, size_t ws_size,
                              hipStream_t stream) {
  const float* x     = (const float*)d_in[0];
  const float* W_ih  = (const float*)d_in[1];
  const float* W_hh  = (const float*)d_in[2];
  const float* b_ih  = (const float*)d_in[3];
  const float* b_hh  = (const float*)d_in[4];
  const float* W_out = (const float*)d_in[5];
  const float* b_out = (const float*)d_in[6];
  float* y           = (float*)d_out;

  const size_t stateBytes = 2ull * B_ * H_ * sizeof(float);
  const size_t bytesPerT = (size_t)B_ * G_ * 2;  // fp16 xg
  int nT = T_;
  while (nT > TS && (size_t)nT * bytesPerT + stateBytes > ws_size) {
    nT >>= 1;
  }

  uint2* xgbuf = (uint2*)d_ws;
  float* hc = (float*)((char*)d_ws + (size_t)nT * bytesPerT);

  for (int t0 = 0; t0 < T_; t0 += nT) {
    xg_gemm<<<dim3((nT * B_) / 64), dim3(256), 0, stream>>>(
        x + (size_t)t0 * B_ * I_, W_ih, b_ih, b_hh, xgbuf);
    lstm_scan<<<dim3(B_), dim3(128), 0, stream>>>(
        xgbuf, W_hh, W_out, b_out, y, hc, t0, nT);
  }
}

// Round 6
// 1749.202 us; speedup vs baseline: 1.0616x; 1.0616x over previous
//
#include <hip/hip_runtime.h>
#include <hip/hip_bf16.h>
#include <hip/hip_fp16.h>

#define B_ 256
#define T_ 4096
#define I_ 64
#define H_ 36
#define G_ 144   // 4*H
#define O_ 2
#define TS 32    // timesteps per LDS tile

typedef __fp16 h2 __attribute__((ext_vector_type(2)));

__device__ __forceinline__ float fsigmoid(float x) {
  float e = __builtin_amdgcn_exp2f(x * -1.442695040888963f);
  return __builtin_amdgcn_rcpf(1.0f + e);
}
__device__ __forceinline__ float ftanh(float x) {
  float e = __builtin_amdgcn_exp2f(x * 2.885390081777926f);
  return 1.0f - 2.0f * __builtin_amdgcn_rcpf(1.0f + e);
}
__device__ __forceinline__ h2 pack2(float lo, float hi) {
  return __builtin_amdgcn_cvt_pkrtz(lo, hi);
}
__device__ __forceinline__ float fdot2(h2 a, h2 b, float c) {
  return __builtin_amdgcn_fdot2(a, b, c, false);
}

// ---------------- xg = x @ W_ih^T + (b_ih+b_hh), fp16-packed ----------------
__global__ __launch_bounds__(256) void xg_gemm(
    const float* __restrict__ x,      // [nT][B][64] (chunk-local)
    const float* __restrict__ W_ih,   // [144][64]
    const float* __restrict__ b_ih,
    const float* __restrict__ b_hh,
    uint2* __restrict__ xg)           // [nT/TS][B][TS][36] uint2
{
  __shared__ float Wt[64 * 145];
  __shared__ float xt[64 * 68];
  __shared__ float bias[G_];

  const int tid = threadIdx.x;
  for (int idx = tid; idx < G_ * I_; idx += 256) {
    int g = idx >> 6, k = idx & 63;
    Wt[k * 145 + g] = W_ih[idx];
  }
  if (tid < G_) bias[tid] = b_ih[tid] + b_hh[tid];

  const long r0 = (long)blockIdx.x * 64;
  const float4* xin = (const float4*)(x + r0 * I_);
#pragma unroll
  for (int v = 0; v < 4; v++) {
    int idx = tid + v * 256;
    float4 d = xin[idx];
    int r = idx >> 4;
    int kk = (idx & 15) << 2;
    xt[(kk + 0) * 68 + r] = d.x;
    xt[(kk + 1) * 68 + r] = d.y;
    xt[(kk + 2) * 68 + r] = d.z;
    xt[(kk + 3) * 68 + r] = d.w;
  }
  __syncthreads();

  const int tr = tid >> 4;            // 0..15 -> 4 rows each
  const int tc = tid & 15;            // only tc<12 compute (12 x 12 cols)

  if (tc < 12) {
    float acc[4][12];
#pragma unroll
    for (int rr = 0; rr < 4; rr++)
#pragma unroll
      for (int q = 0; q < 12; q++) acc[rr][q] = 0.0f;

#pragma unroll 4
    for (int k = 0; k < 64; k++) {
      float4 xv = *(const float4*)&xt[k * 68 + (tr << 2)];
      const float* wr = &Wt[k * 145 + tc];
#pragma unroll
      for (int q = 0; q < 12; q++) {
        float w = wr[12 * q];
        acc[0][q] = fmaf(xv.x, w, acc[0][q]);
        acc[1][q] = fmaf(xv.y, w, acc[1][q]);
        acc[2][q] = fmaf(xv.z, w, acc[2][q]);
        acc[3][q] = fmaf(xv.w, w, acc[3][q]);
      }
    }

#pragma unroll
    for (int rr = 0; rr < 4; rr++) {
      long r = r0 + (tr << 2) + rr;          // r = t_local*B + b
      int t = (int)(r >> 8);                 // B_ = 256
      int b = (int)(r & 255);
      uint2* out = xg + (((size_t)(t >> 5) * B_ + b) * TS + (t & 31)) * 36;
#pragma unroll
      for (int jq = 0; jq < 3; jq++) {
        int j = tc + 12 * jq;
        float ai = acc[rr][jq]     + bias[j];
        float af = acc[rr][jq + 3] + bias[j + 36];
        float ag = acc[rr][jq + 6] + bias[j + 72];
        float ao = acc[rr][jq + 9] + bias[j + 108];
        uint2 u;
        u.x = __builtin_bit_cast(unsigned int, pack2(ai, af));
        u.y = __builtin_bit_cast(unsigned int, pack2(ag, ao));
        out[j] = u;
      }
    }
  }
}

// broadcast helper: build (h[2t], h[2t+1]) half2 on even lanes, no DS ops.
__device__ __forceinline__ int pack_pair_dpp(float hj) {
  // quad_perm [1,1,3,3]: even lanes receive neighbor lane j+1
  int hn_i = __builtin_amdgcn_update_dpp(0, __float_as_int(hj), 0xF5, 0xF, 0xF, true);
  float hn = __int_as_float(hn_i);
  return __builtin_bit_cast(int, pack2(hj, hn));
}

// ---------------- LSTM scan: wave0 = compute (NO VMEM in loop), wave1 = stage + y-flush ----------------
__global__ __launch_bounds__(128, 1) void lstm_scan(
    const uint2* __restrict__ xgT,    // [nT/TS][B][TS][36] uint2 (chunk-local)
    const float* __restrict__ W_hh,   // [144][36]
    const float* __restrict__ W_out,  // [2][36]
    const float* __restrict__ b_out,  // [2]
    float* __restrict__ y,            // [T][B][2] fp32
    float* __restrict__ hc,           // [2][B][36]
    int t0, int nT)
{
  __shared__ float4 buf4[2][576];     // 2 x 32steps x 36 x 8B = 18.4 KiB
  __shared__ float ybuf[2][TS][2];    // staged y pairs, double-buffered
  const int b = blockIdx.x;
  const int tid = threadIdx.x;
  const int j = tid & 63;
  const int ntiles = nT / TS;

  h2 wpi[18], wpf[18], wpg[18], wpo[18];
  float hj = 0.0f, cj = 0.0f, yb = 0.0f;
  int jj = 0;

  if (tid < 64) {
    if (j < H_) {
#pragma unroll
      for (int t = 0; t < 18; t++) {
        wpi[t] = pack2(W_hh[j * H_ + 2 * t],             W_hh[j * H_ + 2 * t + 1]);
        wpf[t] = pack2(W_hh[(j + H_) * H_ + 2 * t],      W_hh[(j + H_) * H_ + 2 * t + 1]);
        wpg[t] = pack2(W_hh[(j + 2 * H_) * H_ + 2 * t],  W_hh[(j + 2 * H_) * H_ + 2 * t + 1]);
        wpo[t] = pack2(W_hh[(j + 3 * H_) * H_ + 2 * t],  W_hh[(j + 3 * H_) * H_ + 2 * t + 1]);
      }
    } else if (j < H_ + O_) {
      const int o = j - H_;
#pragma unroll
      for (int t = 0; t < 18; t++) {
        wpi[t] = pack2(W_out[o * H_ + 2 * t], W_out[o * H_ + 2 * t + 1]);
        wpf[t] = pack2(0.f, 0.f); wpg[t] = pack2(0.f, 0.f); wpo[t] = pack2(0.f, 0.f);
      }
      yb = b_out[o];
    } else {
#pragma unroll
      for (int t = 0; t < 18; t++) {
        wpi[t] = pack2(0.f, 0.f); wpf[t] = pack2(0.f, 0.f);
        wpg[t] = pack2(0.f, 0.f); wpo[t] = pack2(0.f, 0.f);
      }
    }
    if (t0 > 0 && j < H_) {
      hj = hc[b * H_ + j];
      cj = hc[B_ * H_ + b * H_ + j];
    }
    jj = (j < H_) ? j : 0;
  }

  // ---- prologue: stage tile 0 (wave 1) ----
  if (tid >= 64) {
    const int pl = tid - 64;
    const float4* src = (const float4*)(xgT + (size_t)b * (TS * 36));
#pragma unroll
    for (int q = 0; q < 9; q++) buf4[0][q * 64 + pl] = src[q * 64 + pl];
  }
  __syncthreads();

  for (int tile = 0; tile < ntiles; ++tile) {
    if (tid >= 64) {
      const int pl = tid - 64;
      // flush previous tile's staged y (off wave0's critical path)
      if (tile >= 1) {
        const int tp = tile - 1;
        const int s = pl >> 1, o = pl & 1;
        const int gt = tp * TS + s - 1;
        float v = ybuf[tp & 1][s][o];
        if (gt >= 0) y[((size_t)(t0 + gt) * B_ + b) * O_ + o] = v;
      }
      if (tile + 1 < ntiles) {
        const float4* src = (const float4*)(xgT + ((size_t)(tile + 1) * B_ + b) * (TS * 36));
        float4* dst = &buf4[(tile + 1) & 1][0];
        float4 tmp[9];
#pragma unroll
        for (int q = 0; q < 9; q++) tmp[q] = src[q * 64 + pl];
#pragma unroll
        for (int q = 0; q < 9; q++) dst[q * 64 + pl] = tmp[q];
      }
    } else {
      const uint2* bp = (const uint2*)&buf4[tile & 1][0];
      uint2 pc = bp[jj];
      for (int s = 0; s < TS; ++s) {
        uint2 pn = bp[((s + 1) & (TS - 1)) * 36 + jj];  // prefetch next step

        // init accumulators (2 per gate -> 9-deep chains)
        h2 v0 = __builtin_bit_cast(h2, pc.x);   // (i,f)
        h2 v1 = __builtin_bit_cast(h2, pc.y);   // (g,o)
        float a_i0, a_f0, a_g0, a_o0;
        if (j < H_) {
          a_i0 = (float)v0.x; a_f0 = (float)v0.y;
          a_g0 = (float)v1.x; a_o0 = (float)v1.y;
        } else {
          a_i0 = yb; a_f0 = 0.f; a_g0 = 0.f; a_o0 = 0.f;
        }
        float a_i1 = 0.f, a_f1 = 0.f, a_g1 = 0.f, a_o1 = 0.f;

        // broadcast h pairs: DPP pack + 18 readlanes (no DS ops on chain)
        int hpi = pack_pair_dpp(hj);
        int hb[18];
#pragma unroll
        for (int t = 0; t < 18; ++t) hb[t] = __builtin_amdgcn_readlane(hpi, 2 * t);
#pragma unroll
        for (int t = 0; t < 18; t += 2) {
          h2 hh0 = __builtin_bit_cast(h2, hb[t]);
          h2 hh1 = __builtin_bit_cast(h2, hb[t + 1]);
          a_i0 = fdot2(wpi[t], hh0, a_i0);  a_i1 = fdot2(wpi[t + 1], hh1, a_i1);
          a_f0 = fdot2(wpf[t], hh0, a_f0);  a_f1 = fdot2(wpf[t + 1], hh1, a_f1);
          a_g0 = fdot2(wpg[t], hh0, a_g0);  a_g1 = fdot2(wpg[t + 1], hh1, a_g1);
          a_o0 = fdot2(wpo[t], hh0, a_o0);  a_o1 = fdot2(wpo[t + 1], hh1, a_o1);
        }
        float a_i = a_i0 + a_i1;

        if (j < H_) {
          float ig = fsigmoid(a_i);
          float fg = fsigmoid(a_f0 + a_f1);
          float gg = ftanh(a_g0 + a_g1);
          float og = fsigmoid(a_o0 + a_o1);
          cj = fg * cj + ig * gg;
          hj = og * ftanh(cj);
        } else if (j < H_ + O_) {
          ybuf[tile & 1][s][j - H_] = a_i;   // LDS stage; no VMEM on the chain
        }
        pc = pn;
      }
    }
    __syncthreads();
  }

  // ---- epilogue ----
  if (tid >= 64) {
    // flush last tile's staged y
    const int pl = tid - 64;
    const int tp = ntiles - 1;
    const int s = pl >> 1, o = pl & 1;
    const int gt = tp * TS + s - 1;
    float v = ybuf[tp & 1][s][o];
    if (gt >= 0) y[((size_t)(t0 + gt) * B_ + b) * O_ + o] = v;
  } else {
    // last y of chunk + state carry
    int hpi = pack_pair_dpp(hj);
    float a = yb;
#pragma unroll
    for (int t = 0; t < 18; ++t) {
      int hb = __builtin_amdgcn_readlane(hpi, 2 * t);
      h2 hh = __builtin_bit_cast(h2, hb);
      a = fdot2(wpi[t], hh, a);
    }
    if (j == H_ || j == H_ + 1) {
      y[((size_t)(t0 + nT - 1) * B_ + b) * O_ + (j - H_)] = a;
    }
    if (j < H_) {
      hc[b * H_ + j] = hj;
      hc[B_ * H_ + b * H_ + j] = cj;
    }
  }
}

extern "C" void kernel_launch(void* const* d_in, const int* in_sizes, int n_in,
                              void* d_out, int out_size, void* d_ws, size_t ws_size,
                              hipStream_t stream) {
  const float* x     = (const float*)d_in[0];
  const float* W_ih  = (const float*)d_in[1];
  const float* W_hh  = (const float*)d_in[2];
  const float* b_ih  = (const float*)d_in[3];
  const float* b_hh  = (const float*)d_in[4];
  const float* W_out = (const float*)d_in[5];
  const float* b_out = (const float*)d_in[6];
  float* y           = (float*)d_out;

  const size_t stateBytes = 2ull * B_ * H_ * sizeof(float);
  const size_t bytesPerT = (size_t)B_ * G_ * 2;  // fp16 xg
  int nT = T_;
  while (nT > TS && (size_t)nT * bytesPerT + stateBytes > ws_size) {
    nT >>= 1;
  }

  uint2* xgbuf = (uint2*)d_ws;
  float* hc = (float*)((char*)d_ws + (size_t)nT * bytesPerT);

  for (int t0 = 0; t0 < T_; t0 += nT) {
    xg_gemm<<<dim3((nT * B_) / 64), dim3(256), 0, stream>>>(
        x + (size_t)t0 * B_ * I_, W_ih, b_ih, b_hh, xgbuf);
    lstm_scan<<<dim3(B_), dim3(128), 0, stream>>>(
        xgbuf, W_hh, W_out, b_out, y, hc, t0, nT);
  }
}

// Round 7
// 1607.286 us; speedup vs baseline: 1.1553x; 1.0883x over previous
//
#include <hip/hip_runtime.h>
#include <hip/hip_bf16.h>
#include <hip/hip_fp16.h>

#define B_ 256
#define T_ 4096
#define I_ 64
#define H_ 36
#define G_ 144   // 4*H
#define O_ 2
#define TS 32    // timesteps per LDS tile

typedef __fp16 h2 __attribute__((ext_vector_type(2)));

__device__ __forceinline__ float fsigmoid(float x) {
  float e = __builtin_amdgcn_exp2f(x * -1.442695040888963f);
  return __builtin_amdgcn_rcpf(1.0f + e);
}
__device__ __forceinline__ float ftanh(float x) {
  float e = __builtin_amdgcn_exp2f(x * 2.885390081777926f);
  return 1.0f - 2.0f * __builtin_amdgcn_rcpf(1.0f + e);
}
__device__ __forceinline__ h2 pack2(float lo, float hi) {
  return __builtin_amdgcn_cvt_pkrtz(lo, hi);
}
__device__ __forceinline__ float fdot2(h2 a, h2 b, float c) {
  return __builtin_amdgcn_fdot2(a, b, c, false);
}

// ---------------- xg = x @ W_ih^T + (b_ih+b_hh), fp16-packed ----------------
__global__ __launch_bounds__(256) void xg_gemm(
    const float* __restrict__ x,      // [nT][B][64] (chunk-local)
    const float* __restrict__ W_ih,   // [144][64]
    const float* __restrict__ b_ih,
    const float* __restrict__ b_hh,
    uint2* __restrict__ xg)           // [nT/TS][B][TS][36] uint2
{
  __shared__ float Wt[64 * 145];
  __shared__ float xt[64 * 68];
  __shared__ float bias[G_];

  const int tid = threadIdx.x;
  for (int idx = tid; idx < G_ * I_; idx += 256) {
    int g = idx >> 6, k = idx & 63;
    Wt[k * 145 + g] = W_ih[idx];
  }
  if (tid < G_) bias[tid] = b_ih[tid] + b_hh[tid];

  const long r0 = (long)blockIdx.x * 64;
  const float4* xin = (const float4*)(x + r0 * I_);
#pragma unroll
  for (int v = 0; v < 4; v++) {
    int idx = tid + v * 256;
    float4 d = xin[idx];
    int r = idx >> 4;
    int kk = (idx & 15) << 2;
    xt[(kk + 0) * 68 + r] = d.x;
    xt[(kk + 1) * 68 + r] = d.y;
    xt[(kk + 2) * 68 + r] = d.z;
    xt[(kk + 3) * 68 + r] = d.w;
  }
  __syncthreads();

  const int tr = tid >> 4;            // 0..15 -> 4 rows each
  const int tc = tid & 15;            // only tc<12 compute (12 x 12 cols)

  if (tc < 12) {
    float acc[4][12];
#pragma unroll
    for (int rr = 0; rr < 4; rr++)
#pragma unroll
      for (int q = 0; q < 12; q++) acc[rr][q] = 0.0f;

#pragma unroll 4
    for (int k = 0; k < 64; k++) {
      float4 xv = *(const float4*)&xt[k * 68 + (tr << 2)];
      const float* wr = &Wt[k * 145 + tc];
#pragma unroll
      for (int q = 0; q < 12; q++) {
        float w = wr[12 * q];
        acc[0][q] = fmaf(xv.x, w, acc[0][q]);
        acc[1][q] = fmaf(xv.y, w, acc[1][q]);
        acc[2][q] = fmaf(xv.z, w, acc[2][q]);
        acc[3][q] = fmaf(xv.w, w, acc[3][q]);
      }
    }

#pragma unroll
    for (int rr = 0; rr < 4; rr++) {
      long r = r0 + (tr << 2) + rr;          // r = t_local*B + b
      int t = (int)(r >> 8);                 // B_ = 256
      int b = (int)(r & 255);
      uint2* out = xg + (((size_t)(t >> 5) * B_ + b) * TS + (t & 31)) * 36;
#pragma unroll
      for (int jq = 0; jq < 3; jq++) {
        int j = tc + 12 * jq;
        float ai = acc[rr][jq]     + bias[j];
        float af = acc[rr][jq + 3] + bias[j + 36];
        float ag = acc[rr][jq + 6] + bias[j + 72];
        float ao = acc[rr][jq + 9] + bias[j + 108];
        uint2 u;
        u.x = __builtin_bit_cast(unsigned int, pack2(ai, af));
        u.y = __builtin_bit_cast(unsigned int, pack2(ag, ao));
        out[j] = u;
      }
    }
  }
}

// broadcast helper: build (h[2t], h[2t+1]) half2 on even lanes, no DS ops.
__device__ __forceinline__ int pack_pair_dpp(float hj) {
  // quad_perm [1,1,3,3]: even lanes receive neighbor lane j+1
  int hn_i = __builtin_amdgcn_update_dpp(0, __float_as_int(hj), 0xF5, 0xF, 0xF, true);
  float hn = __int_as_float(hn_i);
  return __builtin_bit_cast(int, pack2(hj, hn));
}

// ---------------- LSTM scan: wave0 = compute (xg tile in REGISTERS, zero DS/VMEM
// in the step chain), wave1 = stage + y-flush ----------------
__global__ __launch_bounds__(128, 1) void lstm_scan(
    const uint2* __restrict__ xgT,    // [nT/TS][B][TS][36] uint2 (chunk-local)
    const float* __restrict__ W_hh,   // [144][36]
    const float* __restrict__ W_out,  // [2][36]
    const float* __restrict__ b_out,  // [2]
    float* __restrict__ y,            // [T][B][2] fp32
    float* __restrict__ hc,           // [2][B][36]
    int t0, int nT)
{
  __shared__ float4 buf4[2][576];     // 2 x 32steps x 36 x 8B = 18.4 KiB
  __shared__ float ybuf[2][TS][2];    // staged y pairs, double-buffered
  const int b = blockIdx.x;
  const int tid = threadIdx.x;
  const int j = tid & 63;
  const int ntiles = nT / TS;

  h2 wpi[18], wpf[18], wpg[18], wpo[18];
  float hj = 0.0f, cj = 0.0f, yb = 0.0f;
  int jj = 0;

  if (tid < 64) {
    if (j < H_) {
#pragma unroll
      for (int t = 0; t < 18; t++) {
        wpi[t] = pack2(W_hh[j * H_ + 2 * t],             W_hh[j * H_ + 2 * t + 1]);
        wpf[t] = pack2(W_hh[(j + H_) * H_ + 2 * t],      W_hh[(j + H_) * H_ + 2 * t + 1]);
        wpg[t] = pack2(W_hh[(j + 2 * H_) * H_ + 2 * t],  W_hh[(j + 2 * H_) * H_ + 2 * t + 1]);
        wpo[t] = pack2(W_hh[(j + 3 * H_) * H_ + 2 * t],  W_hh[(j + 3 * H_) * H_ + 2 * t + 1]);
      }
    } else if (j < H_ + O_) {
      const int o = j - H_;
#pragma unroll
      for (int t = 0; t < 18; t++) {
        wpi[t] = pack2(W_out[o * H_ + 2 * t], W_out[o * H_ + 2 * t + 1]);
        wpf[t] = pack2(0.f, 0.f); wpg[t] = pack2(0.f, 0.f); wpo[t] = pack2(0.f, 0.f);
      }
      yb = b_out[o];
    } else {
#pragma unroll
      for (int t = 0; t < 18; t++) {
        wpi[t] = pack2(0.f, 0.f); wpf[t] = pack2(0.f, 0.f);
        wpg[t] = pack2(0.f, 0.f); wpo[t] = pack2(0.f, 0.f);
      }
    }
    if (t0 > 0 && j < H_) {
      hj = hc[b * H_ + j];
      cj = hc[B_ * H_ + b * H_ + j];
    }
    jj = (j < H_) ? j : 0;
  }

  // ---- prologue: stage tile 0 (wave 1) ----
  if (tid >= 64) {
    const int pl = tid - 64;
    const float4* src = (const float4*)(xgT + (size_t)b * (TS * 36));
#pragma unroll
    for (int q = 0; q < 9; q++) buf4[0][q * 64 + pl] = src[q * 64 + pl];
  }
  __syncthreads();

  for (int tile = 0; tile < ntiles; ++tile) {
    if (tid >= 64) {
      const int pl = tid - 64;
      // flush previous tile's staged y (off wave0's critical path)
      if (tile >= 1) {
        const int tp = tile - 1;
        const int s = pl >> 1, o = pl & 1;
        const int gt = tp * TS + s - 1;
        float v = ybuf[tp & 1][s][o];
        if (gt >= 0) y[((size_t)(t0 + gt) * B_ + b) * O_ + o] = v;
      }
      if (tile + 1 < ntiles) {
        const float4* src = (const float4*)(xgT + ((size_t)(tile + 1) * B_ + b) * (TS * 36));
        float4* dst = &buf4[(tile + 1) & 1][0];
        float4 tmp[9];
#pragma unroll
        for (int q = 0; q < 9; q++) tmp[q] = src[q * 64 + pl];
#pragma unroll
        for (int q = 0; q < 9; q++) dst[q * 64 + pl] = tmp[q];
      }
    } else {
      const uint2* bp = (const uint2*)&buf4[tile & 1][0];
      // bulk-load the whole tile into registers: the step chain has ZERO DS ops
      uint2 xr[TS];
#pragma unroll
      for (int s = 0; s < TS; ++s) xr[s] = bp[s * 36 + jj];

#pragma unroll
      for (int s = 0; s < TS; ++s) {
        // init accumulators (2 per gate -> 9-deep chains)
        h2 v0 = __builtin_bit_cast(h2, xr[s].x);   // (i,f)
        h2 v1 = __builtin_bit_cast(h2, xr[s].y);   // (g,o)
        float a_i0, a_f0, a_g0, a_o0;
        if (j < H_) {
          a_i0 = (float)v0.x; a_f0 = (float)v0.y;
          a_g0 = (float)v1.x; a_o0 = (float)v1.y;
        } else {
          a_i0 = yb; a_f0 = 0.f; a_g0 = 0.f; a_o0 = 0.f;
        }
        float a_i1 = 0.f, a_f1 = 0.f, a_g1 = 0.f, a_o1 = 0.f;

        // broadcast h pairs: DPP pack + 18 readlanes (no DS ops on chain)
        int hpi = pack_pair_dpp(hj);
        int hb[18];
#pragma unroll
        for (int t = 0; t < 18; ++t) hb[t] = __builtin_amdgcn_readlane(hpi, 2 * t);
#pragma unroll
        for (int t = 0; t < 18; t += 2) {
          h2 hh0 = __builtin_bit_cast(h2, hb[t]);
          h2 hh1 = __builtin_bit_cast(h2, hb[t + 1]);
          a_i0 = fdot2(wpi[t], hh0, a_i0);  a_i1 = fdot2(wpi[t + 1], hh1, a_i1);
          a_f0 = fdot2(wpf[t], hh0, a_f0);  a_f1 = fdot2(wpf[t + 1], hh1, a_f1);
          a_g0 = fdot2(wpg[t], hh0, a_g0);  a_g1 = fdot2(wpg[t + 1], hh1, a_g1);
          a_o0 = fdot2(wpo[t], hh0, a_o0);  a_o1 = fdot2(wpo[t + 1], hh1, a_o1);
        }
        float a_i = a_i0 + a_i1;

        if (j < H_) {
          float ig = fsigmoid(a_i);
          float fg = fsigmoid(a_f0 + a_f1);
          float gg = ftanh(a_g0 + a_g1);
          float og = fsigmoid(a_o0 + a_o1);
          cj = fg * cj + ig * gg;
          hj = og * ftanh(cj);
        } else if (j < H_ + O_) {
          ybuf[tile & 1][s][j - H_] = a_i;   // LDS stage; no VMEM on the chain
        }
      }
    }
    __syncthreads();
  }

  // ---- epilogue ----
  if (tid >= 64) {
    // flush last tile's staged y
    const int pl = tid - 64;
    const int tp = ntiles - 1;
    const int s = pl >> 1, o = pl & 1;
    const int gt = tp * TS + s - 1;
    float v = ybuf[tp & 1][s][o];
    if (gt >= 0) y[((size_t)(t0 + gt) * B_ + b) * O_ + o] = v;
  } else {
    // last y of chunk + state carry
    int hpi = pack_pair_dpp(hj);
    float a = yb;
#pragma unroll
    for (int t = 0; t < 18; ++t) {
      int hb = __builtin_amdgcn_readlane(hpi, 2 * t);
      h2 hh = __builtin_bit_cast(h2, hb);
      a = fdot2(wpi[t], hh, a);
    }
    if (j == H_ || j == H_ + 1) {
      y[((size_t)(t0 + nT - 1) * B_ + b) * O_ + (j - H_)] = a;
    }
    if (j < H_) {
      hc[b * H_ + j] = hj;
      hc[B_ * H_ + b * H_ + j] = cj;
    }
  }
}

extern "C" void kernel_launch(void* const* d_in, const int* in_sizes, int n_in,
                              void* d_out, int out_size, void* d_ws, size_t ws_size,
                              hipStream_t stream) {
  const float* x     = (const float*)d_in[0];
  const float* W_ih  = (const float*)d_in[1];
  const float* W_hh  = (const float*)d_in[2];
  const float* b_ih  = (const float*)d_in[3];
  const float* b_hh  = (const float*)d_in[4];
  const float* W_out = (const float*)d_in[5];
  const float* b_out = (const float*)d_in[6];
  float* y           = (float*)d_out;

  const size_t stateBytes = 2ull * B_ * H_ * sizeof(float);
  const size_t bytesPerT = (size_t)B_ * G_ * 2;  // fp16 xg
  int nT = T_;
  while (nT > TS && (size_t)nT * bytesPerT + stateBytes > ws_size) {
    nT >>= 1;
  }

  uint2* xgbuf = (uint2*)d_ws;
  float* hc = (float*)((char*)d_ws + (size_t)nT * bytesPerT);

  for (int t0 = 0; t0 < T_; t0 += nT) {
    xg_gemm<<<dim3((nT * B_) / 64), dim3(256), 0, stream>>>(
        x + (size_t)t0 * B_ * I_, W_ih, b_ih, b_hh, xgbuf);
    lstm_scan<<<dim3(B_), dim3(128), 0, stream>>>(
        xgbuf, W_hh, W_out, b_out, y, hc, t0, nT);
  }
}